// Round 16
// baseline (18001.599 us; speedup 1.0000x reference)
//
#include <hip/hip_runtime.h>
#include <stdint.h>

#define STEPS 100

// ---------------------------------------------------------------------------
// Threefry2x32 (JAX-exact, 20 rounds)
// ---------------------------------------------------------------------------
__device__ __forceinline__ uint32_t rotl32(uint32_t v, int r) {
  return (v << r) | (v >> (32 - r));
}

__device__ __forceinline__ void tf2x32(uint32_t k0, uint32_t k1,
                                       uint32_t x0, uint32_t x1,
                                       uint32_t& o0, uint32_t& o1) {
  uint32_t ks2 = k0 ^ k1 ^ 0x1BD11BDAu;
  x0 += k0; x1 += k1;
#define RND(r) { x0 += x1; x1 = rotl32(x1, (r)); x1 ^= x0; }
  RND(13) RND(15) RND(26) RND(6)
  x0 += k1;  x1 += ks2 + 1u;
  RND(17) RND(29) RND(16) RND(24)
  x0 += ks2; x1 += k0 + 2u;
  RND(13) RND(15) RND(26) RND(6)
  x0 += k0;  x1 += k1 + 3u;
  RND(17) RND(29) RND(16) RND(24)
  x0 += k1;  x1 += ks2 + 4u;
  RND(13) RND(15) RND(26) RND(6)
  x0 += ks2; x1 += k0 + 5u;
#undef RND
  o0 = x0; o1 = x1;
}

__global__ void keys_k(uint32_t* __restrict__ kb) {
  int i = threadIdx.x;
  if (i < STEPS) {
    uint32_t a, b;
    tf2x32(0u, 42u, 0u, (uint32_t)i, a, b);
    kb[2 * i] = a;
    kb[2 * i + 1] = b;
  }
}

__global__ void wt_k(const float* __restrict__ w2, float* __restrict__ wT) {
  int i = blockIdx.x * blockDim.x + threadIdx.x;
  if (i >= 25000) return;
  int oc = i / 500, q = i % 500;
  wT[q * 50 + oc] = w2[i];
}

// wf0 transpose, padded: wf0T[k*256 + n] = (n<200) ? wf0[n*2450+k] : 0
__global__ void wf0t_k(const float* __restrict__ wf0,
                       float* __restrict__ wf0T) {
  int i = blockIdx.x * blockDim.x + threadIdx.x;
  if (i >= 2450 * 256) return;
  int k = i >> 8, n = i & 255;
  wf0T[i] = (n < 200) ? wf0[n * 2450 + k] : 0.f;
}

// ---------------------------------------------------------------------------
// PERSISTENT per-sample kernel v7 = v6 body with __launch_bounds__(512,1):
// 256-reg budget so the weight-stationary P2 live set (~180 regs) fits with
// ZERO scratch spill (R15 at (512,2)/128 regs spilled 5.5 GB to HBM).
// Occupancy: 1 block/CU (8 waves); ILP-28 FMA chains carry the latency.
// Summation order (ic,ky,kx) ascending everywhere -> bitwise-identical.
// ---------------------------------------------------------------------------
__global__ __launch_bounds__(512, 1) void step_all_k(
    const float* __restrict__ x, const float* __restrict__ w1,
    const float* __restrict__ wT, const uint32_t* __restrict__ kb,
    uint32_t* __restrict__ sp2g) {
  __shared__ float  xh_l[784];         // |x|/2
  __shared__ float  xs_l[784];         // sign(x)
  __shared__ float  pois_l[784];       // poisson spikes (fp32)
  __shared__ float  sp1_l[20 * 196];   // pool1 spikes (fp32)
  __shared__ int8_t s2_l[50 * 196];    // conv2 spikes (bytes)
  __shared__ float  m2s_l[2450];       // pool2 membranes

  const int b  = blockIdx.x;
  const int t  = threadIdx.x;
  // P1 mapping
  const int lq = t & 255;
  const int ohu = __builtin_amdgcn_readfirstlane(t >> 8);
  const bool act1 = lq < 196;
  const int qy = lq / 14, qx = lq % 14;
  // P2 mapping: thread = (oc, row-pair)
  const bool act2 = t < 350;
  const int oc2 = t / 7;              // 0..49
  const int rp  = t % 7;              // 0..6
  const int y0  = 2 * rp;

  for (int p = t; p < 784; p += 512) {
    float xv = x[b * 784 + p];
    xh_l[p] = fabsf(xv) * 0.5f;
    xs_l[p] = (xv > 0.f) ? 1.f : ((xv < 0.f) ? -1.f : 0.f);
  }
  for (int i = t; i < 2450; i += 512) m2s_l[i] = 0.f;

  // persistent register membranes
  float m1r[4][10], m1sr[10];          // conv1 + pool1 (P1 mapping)
  float m2r[2][14];                    // conv2 (P2 mapping)
#pragma unroll
  for (int i = 0; i < 10; ++i) {
    m1sr[i] = 0.f;
#pragma unroll
    for (int tt = 0; tt < 4; ++tt) m1r[tt][i] = 0.f;
  }
#pragma unroll
  for (int r = 0; r < 2; ++r)
#pragma unroll
    for (int xx = 0; xx < 14; ++xx) m2r[r][xx] = 0.f;
  __syncthreads();

  // poisson for step 0
  {
    uint32_t k0 = kb[0], k1 = kb[1];
    for (int p = t; p < 784; p += 512) {
      uint32_t o0, o1;
      tf2x32(k0, k1, 0u, (uint32_t)(b * 784 + p), o0, o1);
      float r = __uint_as_float(((o0 ^ o1) >> 9) | 0x3F800000u) - 1.0f;
      pois_l[p] = (xh_l[p] > r) ? xs_l[p] : 0.f;
    }
  }
  __syncthreads();

  for (int s = 0; s < STEPS; ++s) {
    // ---- P1: conv1 (10 oc of this half) + fire + pool1 + fire ----
    if (act1) {
      float acc[4][10];
#pragma unroll
      for (int tt = 0; tt < 4; ++tt)
#pragma unroll
        for (int i = 0; i < 10; ++i) acc[tt][i] = 0.f;
#pragma unroll
      for (int tt = 0; tt < 4; ++tt) {
        int y = 2 * qy + (tt >> 1);
        int xx = 2 * qx + (tt & 1);
#pragma unroll
        for (int ky = 0; ky < 5; ++ky) {
          int iy = y + ky - 2;
          if (iy < 0 || iy >= 28) continue;
#pragma unroll
          for (int kx = 0; kx < 5; ++kx) {
            int ix = xx + kx - 2;
            if (ix < 0 || ix >= 28) continue;
            float v = pois_l[iy * 28 + ix];
#pragma unroll
            for (int i = 0; i < 10; ++i)
              acc[tt][i] += w1[(ohu * 10 + i) * 25 + ky * 5 + kx] * v;
          }
        }
      }
#pragma unroll
      for (int i = 0; i < 10; ++i) {
        float s4[4];
#pragma unroll
        for (int tt = 0; tt < 4; ++tt) {
          float m = m1r[tt][i] + acc[tt][i];
          float sp = 0.f;
          if (m > 1.0f) { sp = 1.f; m = 0.f; }
          m1r[tt][i] = m;
          s4[tt] = sp;
        }
        float a = 0.25f * (((s4[0] + s4[1]) + s4[2]) + s4[3]);
        float mm = m1sr[i] + a;
        float spp = 0.f;
        if (mm > 0.75f) { spp = 1.f; mm = 0.f; }
        m1sr[i] = mm;
        sp1_l[(ohu * 10 + i) * 196 + lq] = spp;
      }
    }
    __syncthreads();

    // ---- P2: conv2 weight-stationary (1 oc x 2 rows per thread) ----
    if (act2) {
      float acc[2][14];
#pragma unroll
      for (int r = 0; r < 2; ++r)
#pragma unroll
        for (int xx = 0; xx < 14; ++xx) acc[r][xx] = 0.f;
      for (int ic = 0; ic < 20; ++ic) {
        // 25 weights for (oc2, ic) into VGPRs (L2-hot, reused 700x)
        float wv[25];
#pragma unroll
        for (int j = 0; j < 25; ++j)
          wv[j] = wT[(ic * 25 + j) * 50 + oc2];
        const float* spi = sp1_l + ic * 196;
#pragma unroll
        for (int ky = 0; ky < 5; ++ky) {
          // two input rows needed for this ky (one per output row)
          float u0[18], u1[18];
          int iy0 = y0 + ky - 2;
          int iy1 = iy0 + 1;
#pragma unroll
          for (int j = 0; j < 18; ++j) {
            int ix = j - 2;
            u0[j] = (iy0 >= 0 && iy0 < 14 && ix >= 0 && ix < 14)
                        ? spi[iy0 * 14 + ix] : 0.f;
            u1[j] = (iy1 >= 0 && iy1 < 14 && ix >= 0 && ix < 14)
                        ? spi[iy1 * 14 + ix] : 0.f;
          }
#pragma unroll
          for (int kx = 0; kx < 5; ++kx) {
            float w = wv[ky * 5 + kx];
#pragma unroll
            for (int xx = 0; xx < 14; ++xx) {
              acc[0][xx] += w * u0[xx + kx];
              acc[1][xx] += w * u1[xx + kx];
            }
          }
        }
      }
#pragma unroll
      for (int r = 0; r < 2; ++r)
#pragma unroll
        for (int xx = 0; xx < 14; ++xx) {
          float m = m2r[r][xx] + acc[r][xx];
          int8_t sp = 0;
          if (m > 1.0f) { sp = 1; m = 0.f; }
          m2r[r][xx] = m;
          s2_l[oc2 * 196 + (y0 + r) * 14 + xx] = sp;
        }
    }
    __syncthreads();

    // ---- P3: pool2 + fire -> ballot pack, + poisson(s+1) ----
#pragma unroll
    for (int i = 0; i < 5; ++i) {
      int e = i * 512 + t;
      bool fire = false;
      if (e < 2450) {
        int oc = e / 49, qq = e % 49;
        int yo = qq / 7, xo = qq % 7;
        int ib = oc * 196 + 2 * yo * 14 + 2 * xo;
        float s00 = (float)s2_l[ib];
        float s01 = (float)s2_l[ib + 1];
        float s10 = (float)s2_l[ib + 14];
        float s11 = (float)s2_l[ib + 15];
        float a = 0.25f * (((s00 + s01) + s10) + s11);
        float m = m2s_l[e] + a;
        if (m > 0.75f) { fire = true; m = 0.f; }
        m2s_l[e] = m;
      }
      unsigned long long mask = __ballot(fire);
      int base = (e & ~63);
      if ((t & 63) == 0 && base < 2450) {
        int d = base >> 5;
        sp2g[b * 7700 + s * 77 + d] = (uint32_t)mask;
        if (base + 32 < 2450)
          sp2g[b * 7700 + s * 77 + d + 1] = (uint32_t)(mask >> 32);
      }
    }
    if (s + 1 < STEPS) {
      uint32_t k0 = kb[2 * (s + 1)], k1 = kb[2 * (s + 1) + 1];
      for (int p = t; p < 784; p += 512) {
        uint32_t o0, o1;
        tf2x32(k0, k1, 0u, (uint32_t)(b * 784 + p), o0, o1);
        float r = __uint_as_float(((o0 ^ o1) >> 9) | 0x3F800000u) - 1.0f;
        pois_l[p] = (xh_l[p] > r) ? xs_l[p] : 0.f;
      }
    }
    __syncthreads();
  }
}

// ---------------------------------------------------------------------------
// fc0 (R14-proven): block = sample, lane = neuron; wave-uniform ctz over
// spike bits; acc += wf0T[k][n] coalesced; k ascending -> bit-identical.
// ---------------------------------------------------------------------------
__global__ __launch_bounds__(256) void fc0f_k(
    const uint32_t* __restrict__ sp2g, const float* __restrict__ wf0T,
    float* __restrict__ Tf0g) {
  __shared__ uint32_t mk[77];
  const int b = blockIdx.x;
  const int n = threadIdx.x;
  float m = 0.f, T = 0.f;
  for (int s = 0; s < STEPS; ++s) {
    __syncthreads();
    if (n < 77) mk[n] = sp2g[b * 7700 + s * 77 + n];
    __syncthreads();
    float acc = 0.f;
    for (int d = 0; d < 77; ++d) {
      uint32_t um = mk[d];
      while (um) {
        int j = __builtin_ctz(um);
        um &= um - 1;
        acc += wf0T[((d << 5) + j) * 256 + n];
      }
    }
    m += acc;
    if (m > 1.0f) { T += 1.f; m = 0.f; }
  }
  if (n < 200) Tf0g[b * 200 + n] = T;
}

// ---------------------------------------------------------------------------
// final: out[b][i] = (Tf0[b][:] . wf1[i][:]) / 1 / 100   (j ascending)
// ---------------------------------------------------------------------------
__global__ void fc1_k(const float* __restrict__ Tf0,
                      const float* __restrict__ wf1,
                      float* __restrict__ out) {
  int idx = blockIdx.x * blockDim.x + threadIdx.x;
  if (idx >= 5120) return;
  int b = idx / 10, i = idx % 10;
  float a = 0.f;
  for (int j = 0; j < 200; ++j) a += Tf0[b * 200 + j] * wf1[i * 200 + j];
  out[idx] = (a / 1.0f) / 100.0f;
}

// ---------------------------------------------------------------------------
extern "C" void kernel_launch(void* const* d_in, const int* in_sizes, int n_in,
                              void* d_out, int out_size, void* d_ws, size_t ws_size,
                              hipStream_t stream) {
  (void)in_sizes; (void)n_in; (void)out_size; (void)ws_size;
  const float* x   = (const float*)d_in[0];
  const float* w1  = (const float*)d_in[1];
  const float* w2  = (const float*)d_in[2];
  const float* wf0 = (const float*)d_in[3];
  const float* wf1 = (const float*)d_in[4];
  float* out = (float*)d_out;
  char* ws = (char*)d_ws;

  // workspace: Tf0 | wT | keys | wf0T | sp2 bitmask  (~18.8 MB)
  const size_t tf0_b  = 512ull * 200 * 4;
  const size_t wt_b   = 25000ull * 4;
  const size_t key_b  = 1024;
  const size_t wf0t_b = 2450ull * 256 * 4;
  float*    Tf0g = (float*)ws;
  float*    wT   = (float*)(ws + tf0_b);
  uint32_t* kb   = (uint32_t*)(ws + tf0_b + wt_b);
  float*    wf0T = (float*)(ws + tf0_b + wt_b + key_b);
  uint32_t* sp2g = (uint32_t*)(ws + tf0_b + wt_b + key_b + wf0t_b);

  keys_k<<<1, 128, 0, stream>>>(kb);
  wt_k<<<98, 256, 0, stream>>>(w2, wT);
  wf0t_k<<<2450, 256, 0, stream>>>(wf0, wf0T);
  step_all_k<<<512, 512, 0, stream>>>(x, w1, wT, kb, sp2g);
  fc0f_k<<<512, 256, 0, stream>>>(sp2g, wf0T, Tf0g);
  fc1_k<<<20, 256, 0, stream>>>(Tf0g, wf1, out);
}

// Round 17
// 15376.657 us; speedup vs baseline: 1.1707x; 1.1707x over previous
//
#include <hip/hip_runtime.h>
#include <stdint.h>

#define STEPS 100

// ---------------------------------------------------------------------------
// Threefry2x32 (JAX-exact, 20 rounds)
// ---------------------------------------------------------------------------
__device__ __forceinline__ uint32_t rotl32(uint32_t v, int r) {
  return (v << r) | (v >> (32 - r));
}

__device__ __forceinline__ void tf2x32(uint32_t k0, uint32_t k1,
                                       uint32_t x0, uint32_t x1,
                                       uint32_t& o0, uint32_t& o1) {
  uint32_t ks2 = k0 ^ k1 ^ 0x1BD11BDAu;
  x0 += k0; x1 += k1;
#define RND(r) { x0 += x1; x1 = rotl32(x1, (r)); x1 ^= x0; }
  RND(13) RND(15) RND(26) RND(6)
  x0 += k1;  x1 += ks2 + 1u;
  RND(17) RND(29) RND(16) RND(24)
  x0 += ks2; x1 += k0 + 2u;
  RND(13) RND(15) RND(26) RND(6)
  x0 += k0;  x1 += k1 + 3u;
  RND(17) RND(29) RND(16) RND(24)
  x0 += k1;  x1 += ks2 + 4u;
  RND(13) RND(15) RND(26) RND(6)
  x0 += ks2; x1 += k0 + 5u;
#undef RND
  o0 = x0; o1 = x1;
}

__global__ void keys_k(uint32_t* __restrict__ kb) {
  int i = threadIdx.x;
  if (i < STEPS) {
    uint32_t a, b;
    tf2x32(0u, 42u, 0u, (uint32_t)i, a, b);
    kb[2 * i] = a;
    kb[2 * i + 1] = b;
  }
}

__global__ void wt_k(const float* __restrict__ w2, float* __restrict__ wT) {
  int i = blockIdx.x * blockDim.x + threadIdx.x;
  if (i >= 25000) return;
  int oc = i / 500, q = i % 500;
  wT[q * 50 + oc] = w2[i];
}

// wf0 transpose, padded: wf0T[k*256 + n] = (n<200) ? wf0[n*2450+k] : 0
__global__ void wf0t_k(const float* __restrict__ wf0,
                       float* __restrict__ wf0T) {
  int i = blockIdx.x * blockDim.x + threadIdx.x;
  if (i >= 2450 * 256) return;
  int k = i >> 8, n = i & 255;
  wf0T[i] = (n < 200) ? wf0[n * 2450 + k] : 0.f;
}

// ---------------------------------------------------------------------------
// PERSISTENT per-sample kernel v8: register-diet P2 to kill the 5.5 GB
// scratch spill (R15/R16). m2 membranes move to LDS; P2 computes its two
// output rows SEQUENTIALLY (unroll-disabled) so the working set is
// acc[14]+u[18]+wv[25] ~ 57 regs; persistent regs = m1r[40]+m1sr[10] only.
// Peak live ~120 < 128-arch -> no scratch. Summation order (ic,ky,kx)
// ascending per output everywhere -> bitwise-identical output.
// ---------------------------------------------------------------------------
__global__ __launch_bounds__(512, 2) void step_all_k(
    const float* __restrict__ x, const float* __restrict__ w1,
    const float* __restrict__ wT, const uint32_t* __restrict__ kb,
    uint32_t* __restrict__ sp2g) {
  __shared__ float  xh_l[784];         // |x|/2
  __shared__ float  xs_l[784];         // sign(x)
  __shared__ float  pois_l[784];       // poisson spikes (fp32)
  __shared__ float  sp1_l[20 * 196];   // pool1 spikes (fp32)
  __shared__ int8_t s2_l[50 * 196];    // conv2 spikes (bytes)
  __shared__ float  m2_l[50 * 196];    // conv2 membranes (39.2 KB)
  __shared__ float  m2s_l[2450];       // pool2 membranes

  const int b  = blockIdx.x;
  const int t  = threadIdx.x;
  // P1 mapping
  const int lq = t & 255;
  const int ohu = __builtin_amdgcn_readfirstlane(t >> 8);
  const bool act1 = lq < 196;
  const int qy = lq / 14, qx = lq % 14;
  // P2 mapping: thread = (oc, row-pair)
  const bool act2 = t < 350;
  const int oc2 = t / 7;              // 0..49
  const int rp  = t % 7;              // 0..6
  const int y0  = 2 * rp;

  for (int p = t; p < 784; p += 512) {
    float xv = x[b * 784 + p];
    xh_l[p] = fabsf(xv) * 0.5f;
    xs_l[p] = (xv > 0.f) ? 1.f : ((xv < 0.f) ? -1.f : 0.f);
  }
  for (int i = t; i < 50 * 196; i += 512) m2_l[i] = 0.f;
  for (int i = t; i < 2450; i += 512) m2s_l[i] = 0.f;

  // persistent register membranes: conv1 + pool1 only
  float m1r[4][10], m1sr[10];
#pragma unroll
  for (int i = 0; i < 10; ++i) {
    m1sr[i] = 0.f;
#pragma unroll
    for (int tt = 0; tt < 4; ++tt) m1r[tt][i] = 0.f;
  }
  __syncthreads();

  // poisson for step 0
  {
    uint32_t k0 = kb[0], k1 = kb[1];
    for (int p = t; p < 784; p += 512) {
      uint32_t o0, o1;
      tf2x32(k0, k1, 0u, (uint32_t)(b * 784 + p), o0, o1);
      float r = __uint_as_float(((o0 ^ o1) >> 9) | 0x3F800000u) - 1.0f;
      pois_l[p] = (xh_l[p] > r) ? xs_l[p] : 0.f;
    }
  }
  __syncthreads();

  for (int s = 0; s < STEPS; ++s) {
    // ---- P1: conv1 (10 oc of this half) + fire + pool1 + fire ----
    if (act1) {
      float acc[4][10];
#pragma unroll
      for (int tt = 0; tt < 4; ++tt)
#pragma unroll
        for (int i = 0; i < 10; ++i) acc[tt][i] = 0.f;
#pragma unroll
      for (int tt = 0; tt < 4; ++tt) {
        int y = 2 * qy + (tt >> 1);
        int xx = 2 * qx + (tt & 1);
#pragma unroll
        for (int ky = 0; ky < 5; ++ky) {
          int iy = y + ky - 2;
          if (iy < 0 || iy >= 28) continue;
#pragma unroll
          for (int kx = 0; kx < 5; ++kx) {
            int ix = xx + kx - 2;
            if (ix < 0 || ix >= 28) continue;
            float v = pois_l[iy * 28 + ix];
#pragma unroll
            for (int i = 0; i < 10; ++i)
              acc[tt][i] += w1[(ohu * 10 + i) * 25 + ky * 5 + kx] * v;
          }
        }
      }
#pragma unroll
      for (int i = 0; i < 10; ++i) {
        float s4[4];
#pragma unroll
        for (int tt = 0; tt < 4; ++tt) {
          float m = m1r[tt][i] + acc[tt][i];
          float sp = 0.f;
          if (m > 1.0f) { sp = 1.f; m = 0.f; }
          m1r[tt][i] = m;
          s4[tt] = sp;
        }
        float a = 0.25f * (((s4[0] + s4[1]) + s4[2]) + s4[3]);
        float mm = m1sr[i] + a;
        float spp = 0.f;
        if (mm > 0.75f) { spp = 1.f; mm = 0.f; }
        m1sr[i] = mm;
        sp1_l[(ohu * 10 + i) * 196 + lq] = spp;
      }
    }
    __syncthreads();

    // ---- P2: conv2 weight-stationary, rows SEQUENTIAL (register diet) ----
    if (act2) {
#pragma unroll 1
      for (int r = 0; r < 2; ++r) {
        int y = y0 + r;
        float acc[14];
#pragma unroll
        for (int xx = 0; xx < 14; ++xx) acc[xx] = 0.f;
        for (int ic = 0; ic < 20; ++ic) {
          float wv[25];
#pragma unroll
          for (int j = 0; j < 25; ++j)
            wv[j] = wT[(ic * 25 + j) * 50 + oc2];
          const float* spi = sp1_l + ic * 196;
#pragma unroll
          for (int ky = 0; ky < 5; ++ky) {
            int iy = y + ky - 2;
            float u[18];
#pragma unroll
            for (int j = 0; j < 18; ++j) {
              int ix = j - 2;
              u[j] = (iy >= 0 && iy < 14 && ix >= 0 && ix < 14)
                         ? spi[iy * 14 + ix] : 0.f;
            }
#pragma unroll
            for (int kx = 0; kx < 5; ++kx) {
              float w = wv[ky * 5 + kx];
#pragma unroll
              for (int xx = 0; xx < 14; ++xx)
                acc[xx] += w * u[xx + kx];
            }
          }
        }
#pragma unroll
        for (int xx = 0; xx < 14; ++xx) {
          int li = oc2 * 196 + y * 14 + xx;
          float m = m2_l[li] + acc[xx];
          int8_t sp = 0;
          if (m > 1.0f) { sp = 1; m = 0.f; }
          m2_l[li] = m;
          s2_l[li] = sp;
        }
      }
    }
    __syncthreads();

    // ---- P3: pool2 + fire -> ballot pack, + poisson(s+1) ----
#pragma unroll
    for (int i = 0; i < 5; ++i) {
      int e = i * 512 + t;
      bool fire = false;
      if (e < 2450) {
        int oc = e / 49, qq = e % 49;
        int yo = qq / 7, xo = qq % 7;
        int ib = oc * 196 + 2 * yo * 14 + 2 * xo;
        float s00 = (float)s2_l[ib];
        float s01 = (float)s2_l[ib + 1];
        float s10 = (float)s2_l[ib + 14];
        float s11 = (float)s2_l[ib + 15];
        float a = 0.25f * (((s00 + s01) + s10) + s11);
        float m = m2s_l[e] + a;
        if (m > 0.75f) { fire = true; m = 0.f; }
        m2s_l[e] = m;
      }
      unsigned long long mask = __ballot(fire);
      int base = (e & ~63);
      if ((t & 63) == 0 && base < 2450) {
        int d = base >> 5;
        sp2g[b * 7700 + s * 77 + d] = (uint32_t)mask;
        if (base + 32 < 2450)
          sp2g[b * 7700 + s * 77 + d + 1] = (uint32_t)(mask >> 32);
      }
    }
    if (s + 1 < STEPS) {
      uint32_t k0 = kb[2 * (s + 1)], k1 = kb[2 * (s + 1) + 1];
      for (int p = t; p < 784; p += 512) {
        uint32_t o0, o1;
        tf2x32(k0, k1, 0u, (uint32_t)(b * 784 + p), o0, o1);
        float r = __uint_as_float(((o0 ^ o1) >> 9) | 0x3F800000u) - 1.0f;
        pois_l[p] = (xh_l[p] > r) ? xs_l[p] : 0.f;
      }
    }
    __syncthreads();
  }
}

// ---------------------------------------------------------------------------
// fc0 (R14-proven): block = sample, lane = neuron; wave-uniform ctz over
// spike bits; acc += wf0T[k][n] coalesced; k ascending -> bit-identical.
// ---------------------------------------------------------------------------
__global__ __launch_bounds__(256) void fc0f_k(
    const uint32_t* __restrict__ sp2g, const float* __restrict__ wf0T,
    float* __restrict__ Tf0g) {
  __shared__ uint32_t mk[77];
  const int b = blockIdx.x;
  const int n = threadIdx.x;
  float m = 0.f, T = 0.f;
  for (int s = 0; s < STEPS; ++s) {
    __syncthreads();
    if (n < 77) mk[n] = sp2g[b * 7700 + s * 77 + n];
    __syncthreads();
    float acc = 0.f;
    for (int d = 0; d < 77; ++d) {
      uint32_t um = mk[d];
      while (um) {
        int j = __builtin_ctz(um);
        um &= um - 1;
        acc += wf0T[((d << 5) + j) * 256 + n];
      }
    }
    m += acc;
    if (m > 1.0f) { T += 1.f; m = 0.f; }
  }
  if (n < 200) Tf0g[b * 200 + n] = T;
}

// ---------------------------------------------------------------------------
// final: out[b][i] = (Tf0[b][:] . wf1[i][:]) / 1 / 100   (j ascending)
// ---------------------------------------------------------------------------
__global__ void fc1_k(const float* __restrict__ Tf0,
                      const float* __restrict__ wf1,
                      float* __restrict__ out) {
  int idx = blockIdx.x * blockDim.x + threadIdx.x;
  if (idx >= 5120) return;
  int b = idx / 10, i = idx % 10;
  float a = 0.f;
  for (int j = 0; j < 200; ++j) a += Tf0[b * 200 + j] * wf1[i * 200 + j];
  out[idx] = (a / 1.0f) / 100.0f;
}

// ---------------------------------------------------------------------------
extern "C" void kernel_launch(void* const* d_in, const int* in_sizes, int n_in,
                              void* d_out, int out_size, void* d_ws, size_t ws_size,
                              hipStream_t stream) {
  (void)in_sizes; (void)n_in; (void)out_size; (void)ws_size;
  const float* x   = (const float*)d_in[0];
  const float* w1  = (const float*)d_in[1];
  const float* w2  = (const float*)d_in[2];
  const float* wf0 = (const float*)d_in[3];
  const float* wf1 = (const float*)d_in[4];
  float* out = (float*)d_out;
  char* ws = (char*)d_ws;

  // workspace: Tf0 | wT | keys | wf0T | sp2 bitmask  (~18.8 MB)
  const size_t tf0_b  = 512ull * 200 * 4;
  const size_t wt_b   = 25000ull * 4;
  const size_t key_b  = 1024;
  const size_t wf0t_b = 2450ull * 256 * 4;
  float*    Tf0g = (float*)ws;
  float*    wT   = (float*)(ws + tf0_b);
  uint32_t* kb   = (uint32_t*)(ws + tf0_b + wt_b);
  float*    wf0T = (float*)(ws + tf0_b + wt_b + key_b);
  uint32_t* sp2g = (uint32_t*)(ws + tf0_b + wt_b + key_b + wf0t_b);

  keys_k<<<1, 128, 0, stream>>>(kb);
  wt_k<<<98, 256, 0, stream>>>(w2, wT);
  wf0t_k<<<2450, 256, 0, stream>>>(wf0, wf0T);
  step_all_k<<<512, 512, 0, stream>>>(x, w1, wT, kb, sp2g);
  fc0f_k<<<512, 256, 0, stream>>>(sp2g, wf0T, Tf0g);
  fc1_k<<<20, 256, 0, stream>>>(Tf0g, wf1, out);
}